// Round 16
// baseline (135.047 us; speedup 1.0000x reference)
//
#include <hip/hip_runtime.h>
#include <hip/hip_bf16.h>

// mLSTM parallel-stabilized cell, MI355X (gfx950).
// B=2, S=2048, H=1024, NH=4, DH=256.
// Identity: max_log_D[i] = cs[i] + m[i], m[i] = prefixmax(ig[j]-cs[j]);
// D[i][j] = exp(a[j]-m[i]), a[j] = ig[j]-cs[j], exponent always <= 0.
// R16: R14 chassis verbatim (dbuf, vmcnt(8), 16-row waves, atomic epilogue,
// separate finalize) with each block split into TWO period-halves (R11's
// proven index transform): 1024 blocks = (bh,it,pi,half). Breaks the
// 32-period sequential chain (worst 16) that pinned R14's wall clock.
// Prep = R13 (coalesced gate GEMV), scan = R9.

#define S_LEN 2048
#define DHD   256
#define NHEAD 4
#define BATCH 2
#define HID   1024
#define BH_CNT (BATCH*NHEAD)

typedef __attribute__((ext_vector_type(8))) short bf16x8;
typedef __attribute__((ext_vector_type(4))) short short4v;
typedef __attribute__((ext_vector_type(4))) float f32x4;

static __device__ __forceinline__ short f2b(float f) {
  __hip_bfloat16 h = __float2bfloat16(f);
  return *reinterpret_cast<short*>(&h);
}

static __device__ __forceinline__ bf16x8 pack8(f32x4 a, f32x4 b) {
  bf16x8 o;
  o[0]=f2b(a[0]); o[1]=f2b(a[1]); o[2]=f2b(a[2]); o[3]=f2b(a[3]);
  o[4]=f2b(b[0]); o[5]=f2b(b[1]); o[6]=f2b(b[2]); o[7]=f2b(b[3]);
  return o;
}

// async global->LDS DMA, 16B/lane. ldsdst wave-uniform; lane l -> dst + l*16B.
static __device__ __forceinline__ void gload16(const void* src, void* ldsdst) {
  __builtin_amdgcn_global_load_lds(
      (const __attribute__((address_space(1))) void*)src,
      (__attribute__((address_space(3))) void*)ldsdst, 16, 0, 0);
}

// ---- kernel 1 (prep): grid 3328 x 256. (verbatim R13)
__global__ __launch_bounds__(256) void prep_kernel(
    const float* __restrict__ q, const float* __restrict__ k, const float* __restrict__ v,
    const float* __restrict__ wi, const float* __restrict__ wf,
    short* __restrict__ Kg, short* __restrict__ Vg,
    float* __restrict__ igA, float* __restrict__ fgA) {
  __shared__ short vt2[32][264];
  const int bx = blockIdx.x, t = threadIdx.x;
  if (bx < 768) {
    const int w = t >> 6, lane = t & 63;
    const int gw = bx*4 + w;             // 0..3071
    const int seg = gw % 3;
    const int rg = gw / 3;               // 0..1023 -> rows rg*4..rg*4+3
    const float* xp = (seg == 0) ? q : (seg == 1) ? k : v;
    const float* wip = wi + (long)seg*HID*NHEAD;
    const float* wfp = wf + (long)seg*HID*NHEAD;
    f32x4 ai[4], af[4];
#pragma unroll
    for (int r = 0; r < 4; r++) { ai[r] = f32x4{0,0,0,0}; af[r] = f32x4{0,0,0,0}; }
    for (int cb = 0; cb < HID; cb += 64) {
      const int c = cb + lane;
      const f32x4 wiv = *(const f32x4*)(wip + (long)c*NHEAD);
      const f32x4 wfv = *(const f32x4*)(wfp + (long)c*NHEAD);
#pragma unroll
      for (int r = 0; r < 4; r++) {
        const float x = xp[(long)(rg*4 + r)*HID + c];
        ai[r] += x * wiv;
        af[r] += x * wfv;
      }
    }
#pragma unroll
    for (int mk = 32; mk >= 1; mk >>= 1)
#pragma unroll
      for (int r = 0; r < 4; r++)
#pragma unroll
        for (int e = 0; e < 4; e++) {
          ai[r][e] += __shfl_xor(ai[r][e], mk);
          af[r][e] += __shfl_xor(af[r][e], mk);
        }
    if (lane == 0) {
#pragma unroll
      for (int r = 0; r < 4; r++) {
        const long row = rg*4 + r;
#pragma unroll
        for (int e = 0; e < 4; e++) {
          unsafeAtomicAdd(&igA[row*NHEAD + e], ai[r][e]);
          unsafeAtomicAdd(&fgA[row*NHEAD + e], af[r][e]);
        }
      }
    }
  } else if (bx < 2816) {
    const int kb = bx - 768;
    const int g_row = kb*2 + (t >> 7);
    const int col = (t & 127) * 8;
    const long off = (long)g_row*HID + col;
    const f32x4 xk0 = *(const f32x4*)(k + off);
    const f32x4 xk1 = *(const f32x4*)(k + off + 4);
    bf16x8 o = pack8(xk0, xk1);
    const int b = g_row >> 11, s = g_row & (S_LEN-1);
    const int hh = col >> 8, d = col & 255;
    const int bh = b*NHEAD + hh, jt = s >> 5, rr = s & 31;
    *(bf16x8*)(Kg + ((long)bh*64 + jt)*8192 + rr*256 + (d ^ ((rr & 7) << 3))) = o;
  } else {
    const int t2 = bx - 2816;              // 0..511
    const int jt = t2 & 63, bhv = t2 >> 6;
    const int b = bhv >> 2, hh = bhv & 3;
    const int j0 = jt * 32;
    const int r0 = t >> 3, c0 = (t & 7) * 32;
    const float* vsrc = v + ((long)(b*S_LEN + j0 + r0))*HID + hh*DHD + c0;
#pragma unroll
    for (int i = 0; i < 4; i++) {
      f32x4 a  = *(const f32x4*)(vsrc + i*8);
      f32x4 bb = *(const f32x4*)(vsrc + i*8 + 4);
      *(bf16x8*)&vt2[r0][c0 + i*8] = pack8(a, bb);
    }
    __syncthreads();
    const long base = ((long)bhv*64 + jt) * 8192;
    const int j = t & 31, dg = t >> 5;
#pragma unroll
    for (int dd = 0; dd < 32; dd++) {
      const int d = dg*32 + dd;
      Vg[base + (long)d*32 + (j ^ (((d >> 1) & 3) << 3))] = vt2[j][d];
    }
  }
}

// ---- kernel 2: per-(b,h) scan (verbatim R9) ----
__global__ void scan_kernel(const float* __restrict__ ig, const float* __restrict__ fg,
                            const float* __restrict__ bi, const float* __restrict__ bf_,
                            float* __restrict__ a_out, float* __restrict__ m_out,
                            float* __restrict__ nf_out) {
  int bh = blockIdx.x, b = bh >> 2, h = bh & 3;
  int t = threadIdx.x;
  __shared__ float tot[256];
  long gbase = (long)b * S_LEN;
  const float biv = bi[h], bfv = bf_[h];
  float ls[8];
  float run = 0.f;
  for (int e = 0; e < 8; e++) {
    int s = t*8 + e;
    float x = fg[(gbase + s)*NHEAD + h] + bfv;
    float l = fminf(x, 0.f) - log1pf(expf(-fabsf(x)));  // stable log_sigmoid
    run += l; ls[e] = run;
  }
  tot[t] = run;
  __syncthreads();
  for (int off = 1; off < 256; off <<= 1) {
    float x = tot[t];
    if (t >= off) x += tot[t - off];
    __syncthreads();
    tot[t] = x;
    __syncthreads();
  }
  float offc = (t == 0) ? 0.f : tot[t-1];
  __syncthreads();
  float av[8], am[8], csv[8];
  float runm = -1e30f;
  for (int e = 0; e < 8; e++) {
    int s = t*8 + e;
    float cs = ls[e] + offc;
    csv[e] = cs;
    float a = (ig[(gbase + s)*NHEAD + h] + biv) - cs;
    av[e] = a;
    runm = fmaxf(runm, a);
    am[e] = runm;
  }
  tot[t] = runm;
  __syncthreads();
  for (int off = 1; off < 256; off <<= 1) {
    float x = tot[t];
    if (t >= off) x = fmaxf(x, tot[t - off]);
    __syncthreads();
    tot[t] = x;
    __syncthreads();
  }
  float offm = (t == 0) ? -1e30f : tot[t-1];
  long obase = (long)bh * S_LEN;
  for (int e = 0; e < 8; e++) {
    int s = t*8 + e;
    float mm = fmaxf(am[e], offm);
    a_out[obase + s]  = av[e];
    m_out[obase + s]  = mm;
    nf_out[obase + s] = expf(-(csv[e] + mm));
  }
}

// ---- kernel 3: partial main. 1024 blocks = (bh, it, parity pi, half).
// 4 waves = 4 row groups of 16; per period one 32-key tile (parity pi),
// dbuf staging quartered across waves, vmcnt(8); atomic O/rowsum epilogue.
// half splits the period range [0,it+1) into [0,nh) / [nh,it+1) — worst
// sequential chain 32 -> 16 periods.
__global__ __launch_bounds__(256, 2) void mlstm_partial_kernel(
    const float* __restrict__ q, const short* __restrict__ Kg, const short* __restrict__ Vg,
    const float* __restrict__ a_arr, const float* __restrict__ m_arr,
    float* __restrict__ outp, float* __restrict__ rsacc) {
  __shared__ alignas(16) short Kst[2][8192];   // [dbuf][32k x 256d swz]
  __shared__ alignas(16) short Vst[2][8192];   // [dbuf][256d x 32j swz]
  __shared__ alignas(16) short plds[4][16*36];
  const int w = threadIdx.x >> 6, lane = threadIdx.x & 63;
  const int lr = lane & 15, g = lane >> 4;
  const int idx = blockIdx.x & 511;
  const int half = blockIdx.x >> 9;
  int pi, it, bh;
  if (idx < 256) { pi = 0; bh = idx & 7; it = 31 - (idx >> 3); }
  else { const int j = idx - 256; pi = 1; bh = j & 7; it = j >> 3; }
  const int b = bh >> 2, h = bh & 3;
  const int R0 = it*64 + w*16;            // wave's 16 rows
  const long arow = (long)bh * S_LEN;
  const int npT = it + 1;                 // total staged periods (tiles 2p+pi)
  const int nh = (npT + 1) >> 1;
  const int p_begin = half ? nh : 0;
  const int p_end   = half ? npT : nh;
  const int dmax = 2*it + (w >> 1) - pi;
  const int pmax = (dmax >= 0) ? (dmax >> 1) : -1;   // wave computes p <= pmax
  const f32x4 zz = {0.f,0.f,0.f,0.f};
  const int sw = (lr & 7) << 3;

  // Q fragments for the wave's 16 rows, cast inline from fp32 source
  bf16x8 qf[8];
  const float* qsrc = q + ((long)(b*S_LEN + R0 + lr))*HID + h*DHD + g*8;
#pragma unroll
  for (int c8 = 0; c8 < 8; c8++) {
    f32x4 u0 = *(const f32x4*)(qsrc + c8*32);
    f32x4 u1 = *(const f32x4*)(qsrc + c8*32 + 4);
    qf[c8] = pack8(u0, u1);
  }
  float mrow[4];
#pragma unroll
  for (int r = 0; r < 4; r++) mrow[r] = m_arr[arow + R0 + g*4 + r];

  f32x4 oacc[16];
#pragma unroll
  for (int t = 0; t < 16; t++) oacc[t] = zz;
  float rs[4] = {0.f,0.f,0.f,0.f};
  short* myp = plds[w];

  // wave w stages quarter w of the K tile and quarter w of the V tile (8 DMA)
  auto STAGE = [&](int pb, int p) {
    const int jts = 2*p + pi;
    const long toff = ((long)bh*64 + jts)*8192 + w*2048 + lane*8;
    short* kdst = &Kst[pb][w*2048];
    short* vdst = &Vst[pb][w*2048];
    const short* ksrc = Kg + toff;
    const short* vsrc = Vg + toff;
#pragma unroll
    for (int u = 0; u < 4; u++) gload16(ksrc + u*512, kdst + u*512);
#pragma unroll
    for (int u = 0; u < 4; u++) gload16(vsrc + u*512, vdst + u*512);
  };

  float aC0 = 0.f, aC1 = 0.f, aN0 = 0.f, aN1 = 0.f;
  if (p_begin < p_end) {
    STAGE(0, p_begin);
    const int j0 = (2*p_begin + pi)*32;
    aC0 = a_arr[arow + j0 + lr]; aC1 = a_arr[arow + j0 + 16 + lr];
  }

  for (int p = p_begin; p < p_end; ++p) {
    const int pb = (p - p_begin) & 1;
    if (p + 1 < p_end) {
      STAGE(pb ^ 1, p + 1);
      { const int j0 = (2*(p+1) + pi)*32;
        aN0 = a_arr[arow + j0 + lr]; aN1 = a_arr[arow + j0 + 16 + lr]; }
      asm volatile("s_waitcnt vmcnt(8)" ::: "memory");  // own 8 DMA of tile p done
    } else {
      asm volatile("s_waitcnt vmcnt(0)" ::: "memory");
    }
    __builtin_amdgcn_s_barrier();

    if (p <= pmax) {
      const int j0 = (2*p + pi)*32;
      const short* Kt = &Kst[pb][0];
      const short* Vt = &Vst[pb][0];
      f32x4 s0 = zz, s1 = zz;
      __builtin_amdgcn_s_setprio(1);
#pragma unroll
      for (int c8 = 0; c8 < 8; c8++) {
        const int ko = lr*256 + ((c8*32 + g*8) ^ sw);
        bf16x8 k0 = *(const bf16x8*)&Kt[ko];
        bf16x8 k1 = *(const bf16x8*)&Kt[ko + 4096];
        s0 = __builtin_amdgcn_mfma_f32_16x16x32_bf16(qf[c8], k0, s0, 0, 0, 0);
        s1 = __builtin_amdgcn_mfma_f32_16x16x32_bf16(qf[c8], k1, s1, 0, 0, 0);
      }
      __builtin_amdgcn_s_setprio(0);
      const bool needmask = (j0 + 31 > R0);
#pragma unroll
      for (int r = 0; r < 4; r++) {
        const int i = R0 + g*4 + r;
        float p0 = s0[r] * 0.0625f * __expf(aC0 - mrow[r]);
        float p1 = s1[r] * 0.0625f * __expf(aC1 - mrow[r]);
        if (needmask) {               // causal mask, diagonal tiles only
          if (j0 + lr > i)      p0 = 0.f;
          if (j0 + 16 + lr > i) p1 = 0.f;
        }
        rs[r] += p0 + p1;
        myp[(g*4 + r)*36 + lr]      = f2b(p0);
        myp[(g*4 + r)*36 + 16 + lr] = f2b(p1);
      }
      // re-fragment P (C-layout) -> A-layout via per-wave LDS
      const short* rp = myp + lr*36 + g*8;
      short4v plo = *(const short4v*)rp;
      short4v phi = *(const short4v*)(rp + 4);
      bf16x8 pa = {plo[0],plo[1],plo[2],plo[3],phi[0],phi[1],phi[2],phi[3]};
      __builtin_amdgcn_s_setprio(1);
#pragma unroll
      for (int t = 0; t < 16; t++) {
        const int d = t*16 + lr;
        const int vo = d*32 + ((g*8) ^ (((d >> 1) & 3) << 3));
        bf16x8 vf = *(const bf16x8*)&Vt[vo];
        oacc[t] = __builtin_amdgcn_mfma_f32_16x16x32_bf16(pa, vf, oacc[t], 0, 0, 0);
      }
      __builtin_amdgcn_s_setprio(0);
    }
    __builtin_amdgcn_s_barrier();
    if (p + 1 < p_end) { aC0 = aN0; aC1 = aN1; }
  }

  // rowsum reduce over the 16 key-columns
#pragma unroll
  for (int r = 0; r < 4; r++)
    for (int mk = 1; mk < 16; mk <<= 1)
      rs[r] += __shfl_xor(rs[r], mk);

  // atomic-accumulate partial O + rowsums
#pragma unroll
  for (int r = 0; r < 4; r++) {
    const int i = R0 + g*4 + r;
    float* orow = outp + ((long)(b*S_LEN + i))*HID + h*DHD + lr;
#pragma unroll
    for (int t = 0; t < 16; t++)
      unsafeAtomicAdd(orow + t*16, oacc[t][r]);
    if (lr == 0)
      unsafeAtomicAdd(&rsacc[arow + i], rs[r]);
  }
}

// ---- kernel 4: finalize — normalizer + per-head LayerNorm (verbatim R10) ----
__global__ __launch_bounds__(256) void finalize_kernel(
    float* __restrict__ outp, const float* __restrict__ rsacc,
    const float* __restrict__ nf_arr, const float* __restrict__ lns) {
  const int bi = blockIdx.x;                  // b*S + i
  const int h = threadIdx.x >> 6, lane = threadIdx.x & 63;
  const int b = bi >> 11, i = bi & (S_LEN-1);
  const int bh = b*NHEAD + h;
  const long roff = (long)bi * HID + (long)h*DHD;
  f32x4 xv = *(const f32x4*)(outp + roff + lane*4);
  const float rsv = rsacc[(long)bh*S_LEN + i];
  const float nfv = nf_arr[(long)bh*S_LEN + i];
  const float inv = 1.f / (fmaxf(fabsf(rsv), nfv) + 1e-6f);
  xv[0]*=inv; xv[1]*=inv; xv[2]*=inv; xv[3]*=inv;
  float sum = xv[0]+xv[1]+xv[2]+xv[3];
  float sq  = xv[0]*xv[0]+xv[1]*xv[1]+xv[2]*xv[2]+xv[3]*xv[3];
  for (int mk = 1; mk < 64; mk <<= 1) {
    sum += __shfl_xor(sum, mk);
    sq  += __shfl_xor(sq,  mk);
  }
  const float mean = sum * (1.f/256.f);
  const float var  = sq * (1.f/256.f) - mean*mean;
  const float rstd = rsqrtf(var + 1e-5f);
  f32x4 sc = *(const f32x4*)(lns + h*DHD + lane*4);
  f32x4 o;
  o[0]=(xv[0]-mean)*rstd*sc[0]; o[1]=(xv[1]-mean)*rstd*sc[1];
  o[2]=(xv[2]-mean)*rstd*sc[2]; o[3]=(xv[3]-mean)*rstd*sc[3];
  *(f32x4*)(outp + roff + lane*4) = o;
}

extern "C" void kernel_launch(void* const* d_in, const int* in_sizes, int n_in,
                              void* d_out, int out_size, void* d_ws, size_t ws_size,
                              hipStream_t stream) {
  const float* q   = (const float*)d_in[0];
  const float* k   = (const float*)d_in[1];
  const float* v   = (const float*)d_in[2];
  const float* wi  = (const float*)d_in[3];
  const float* bi  = (const float*)d_in[4];
  const float* wf  = (const float*)d_in[5];
  const float* bf_ = (const float*)d_in[6];
  const float* lns = (const float*)d_in[7];
  float* outp = (float*)d_out;

  char* ws = (char*)d_ws;
  const long nelem = (long)BH_CNT * S_LEN * DHD;      // 4,194,304
  short* Kg  = (short*)ws;
  short* Vg  = Kg + nelem;
  float* igA = (float*)(ws + 2*nelem*sizeof(short));
  float* fgA = igA + (long)BATCH*S_LEN*NHEAD;
  float* aA  = fgA + (long)BATCH*S_LEN*NHEAD;
  float* mA  = aA + (long)BH_CNT*S_LEN;
  float* nfA = mA + (long)BH_CNT*S_LEN;
  float* rsA = nfA + (long)BH_CNT*S_LEN;

  // zero accumulators: gates, output, rowsums
  hipMemsetAsync(igA, 0, 2 * (size_t)BATCH*S_LEN*NHEAD * sizeof(float), stream);
  hipMemsetAsync(outp, 0, (size_t)out_size * sizeof(float), stream);
  hipMemsetAsync(rsA, 0, (size_t)BH_CNT * S_LEN * sizeof(float), stream);

  prep_kernel<<<3328, 256, 0, stream>>>(q, k, v, wi, wf, Kg, Vg, igA, fgA);
  scan_kernel<<<BH_CNT, 256, 0, stream>>>(igA, fgA, bi, bf_, aA, mA, nfA);
  mlstm_partial_kernel<<<1024, 256, 0, stream>>>(q, Kg, Vg, aA, mA, outp, rsA);
  finalize_kernel<<<BATCH*S_LEN, 256, 0, stream>>>(outp, rsA, nfA, lns);
}

// Round 17
// 105.865 us; speedup vs baseline: 1.2757x; 1.2757x over previous
//
#include <hip/hip_runtime.h>
#include <hip/hip_bf16.h>

// mLSTM parallel-stabilized cell, MI355X (gfx950).
// B=2, S=2048, H=1024, NH=4, DH=256.
// Identity: max_log_D[i] = cs[i] + m[i], m[i] = prefixmax(ig[j]-cs[j]);
// D[i][j] = exp(a[j]-m[i]), a[j] = ig[j]-cs[j], exponent always <= 0.
// R17: R14 chassis (512 blocks, 16-row waves, atomic epilogue, finalize)
// with SINGLE-BUFFERED V tile (consumed late -> staged-per-period, waited
// just before PV): LDS 70->52.5 KB => 3 blocks/CU. K stays double-buffered.
// 3 barriers/period; FIFO-robust vmcnt: W1=8/4, W2=4/0 (count only DMAs
// younger than target; immune to a-load placement). Prep=R13, scan=R9.

#define S_LEN 2048
#define DHD   256
#define NHEAD 4
#define BATCH 2
#define HID   1024
#define BH_CNT (BATCH*NHEAD)

typedef __attribute__((ext_vector_type(8))) short bf16x8;
typedef __attribute__((ext_vector_type(4))) short short4v;
typedef __attribute__((ext_vector_type(4))) float f32x4;

static __device__ __forceinline__ short f2b(float f) {
  __hip_bfloat16 h = __float2bfloat16(f);
  return *reinterpret_cast<short*>(&h);
}

static __device__ __forceinline__ bf16x8 pack8(f32x4 a, f32x4 b) {
  bf16x8 o;
  o[0]=f2b(a[0]); o[1]=f2b(a[1]); o[2]=f2b(a[2]); o[3]=f2b(a[3]);
  o[4]=f2b(b[0]); o[5]=f2b(b[1]); o[6]=f2b(b[2]); o[7]=f2b(b[3]);
  return o;
}

// async global->LDS DMA, 16B/lane. ldsdst wave-uniform; lane l -> dst + l*16B.
static __device__ __forceinline__ void gload16(const void* src, void* ldsdst) {
  __builtin_amdgcn_global_load_lds(
      (const __attribute__((address_space(1))) void*)src,
      (__attribute__((address_space(3))) void*)ldsdst, 16, 0, 0);
}

// ---- kernel 1 (prep): grid 3328 x 256. (verbatim R13)
__global__ __launch_bounds__(256) void prep_kernel(
    const float* __restrict__ q, const float* __restrict__ k, const float* __restrict__ v,
    const float* __restrict__ wi, const float* __restrict__ wf,
    short* __restrict__ Kg, short* __restrict__ Vg,
    float* __restrict__ igA, float* __restrict__ fgA) {
  __shared__ short vt2[32][264];
  const int bx = blockIdx.x, t = threadIdx.x;
  if (bx < 768) {
    const int w = t >> 6, lane = t & 63;
    const int gw = bx*4 + w;             // 0..3071
    const int seg = gw % 3;
    const int rg = gw / 3;               // 0..1023 -> rows rg*4..rg*4+3
    const float* xp = (seg == 0) ? q : (seg == 1) ? k : v;
    const float* wip = wi + (long)seg*HID*NHEAD;
    const float* wfp = wf + (long)seg*HID*NHEAD;
    f32x4 ai[4], af[4];
#pragma unroll
    for (int r = 0; r < 4; r++) { ai[r] = f32x4{0,0,0,0}; af[r] = f32x4{0,0,0,0}; }
    for (int cb = 0; cb < HID; cb += 64) {
      const int c = cb + lane;
      const f32x4 wiv = *(const f32x4*)(wip + (long)c*NHEAD);
      const f32x4 wfv = *(const f32x4*)(wfp + (long)c*NHEAD);
#pragma unroll
      for (int r = 0; r < 4; r++) {
        const float x = xp[(long)(rg*4 + r)*HID + c];
        ai[r] += x * wiv;
        af[r] += x * wfv;
      }
    }
#pragma unroll
    for (int mk = 32; mk >= 1; mk >>= 1)
#pragma unroll
      for (int r = 0; r < 4; r++)
#pragma unroll
        for (int e = 0; e < 4; e++) {
          ai[r][e] += __shfl_xor(ai[r][e], mk);
          af[r][e] += __shfl_xor(af[r][e], mk);
        }
    if (lane == 0) {
#pragma unroll
      for (int r = 0; r < 4; r++) {
        const long row = rg*4 + r;
#pragma unroll
        for (int e = 0; e < 4; e++) {
          unsafeAtomicAdd(&igA[row*NHEAD + e], ai[r][e]);
          unsafeAtomicAdd(&fgA[row*NHEAD + e], af[r][e]);
        }
      }
    }
  } else if (bx < 2816) {
    const int kb = bx - 768;
    const int g_row = kb*2 + (t >> 7);
    const int col = (t & 127) * 8;
    const long off = (long)g_row*HID + col;
    const f32x4 xk0 = *(const f32x4*)(k + off);
    const f32x4 xk1 = *(const f32x4*)(k + off + 4);
    bf16x8 o = pack8(xk0, xk1);
    const int b = g_row >> 11, s = g_row & (S_LEN-1);
    const int hh = col >> 8, d = col & 255;
    const int bh = b*NHEAD + hh, jt = s >> 5, rr = s & 31;
    *(bf16x8*)(Kg + ((long)bh*64 + jt)*8192 + rr*256 + (d ^ ((rr & 7) << 3))) = o;
  } else {
    const int t2 = bx - 2816;              // 0..511
    const int jt = t2 & 63, bhv = t2 >> 6;
    const int b = bhv >> 2, hh = bhv & 3;
    const int j0 = jt * 32;
    const int r0 = t >> 3, c0 = (t & 7) * 32;
    const float* vsrc = v + ((long)(b*S_LEN + j0 + r0))*HID + hh*DHD + c0;
#pragma unroll
    for (int i = 0; i < 4; i++) {
      f32x4 a  = *(const f32x4*)(vsrc + i*8);
      f32x4 bb = *(const f32x4*)(vsrc + i*8 + 4);
      *(bf16x8*)&vt2[r0][c0 + i*8] = pack8(a, bb);
    }
    __syncthreads();
    const long base = ((long)bhv*64 + jt) * 8192;
    const int j = t & 31, dg = t >> 5;
#pragma unroll
    for (int dd = 0; dd < 32; dd++) {
      const int d = dg*32 + dd;
      Vg[base + (long)d*32 + (j ^ (((d >> 1) & 3) << 3))] = vt2[j][d];
    }
  }
}

// ---- kernel 2: per-(b,h) scan (verbatim R9) ----
__global__ void scan_kernel(const float* __restrict__ ig, const float* __restrict__ fg,
                            const float* __restrict__ bi, const float* __restrict__ bf_,
                            float* __restrict__ a_out, float* __restrict__ m_out,
                            float* __restrict__ nf_out) {
  int bh = blockIdx.x, b = bh >> 2, h = bh & 3;
  int t = threadIdx.x;
  __shared__ float tot[256];
  long gbase = (long)b * S_LEN;
  const float biv = bi[h], bfv = bf_[h];
  float ls[8];
  float run = 0.f;
  for (int e = 0; e < 8; e++) {
    int s = t*8 + e;
    float x = fg[(gbase + s)*NHEAD + h] + bfv;
    float l = fminf(x, 0.f) - log1pf(expf(-fabsf(x)));  // stable log_sigmoid
    run += l; ls[e] = run;
  }
  tot[t] = run;
  __syncthreads();
  for (int off = 1; off < 256; off <<= 1) {
    float x = tot[t];
    if (t >= off) x += tot[t - off];
    __syncthreads();
    tot[t] = x;
    __syncthreads();
  }
  float offc = (t == 0) ? 0.f : tot[t-1];
  __syncthreads();
  float av[8], am[8], csv[8];
  float runm = -1e30f;
  for (int e = 0; e < 8; e++) {
    int s = t*8 + e;
    float cs = ls[e] + offc;
    csv[e] = cs;
    float a = (ig[(gbase + s)*NHEAD + h] + biv) - cs;
    av[e] = a;
    runm = fmaxf(runm, a);
    am[e] = runm;
  }
  tot[t] = runm;
  __syncthreads();
  for (int off = 1; off < 256; off <<= 1) {
    float x = tot[t];
    if (t >= off) x = fmaxf(x, tot[t - off]);
    __syncthreads();
    tot[t] = x;
    __syncthreads();
  }
  float offm = (t == 0) ? -1e30f : tot[t-1];
  long obase = (long)bh * S_LEN;
  for (int e = 0; e < 8; e++) {
    int s = t*8 + e;
    float mm = fmaxf(am[e], offm);
    a_out[obase + s]  = av[e];
    m_out[obase + s]  = mm;
    nf_out[obase + s] = expf(-(csv[e] + mm));
  }
}

// ---- kernel 3: partial main. 512 blocks = (bh, it, parity pi) (R14 decode).
// 4 waves = 4 row groups of 16; per period one 32-key tile (parity pi).
// K double-buffered (prefetch p+1), V SINGLE-buffered (staged this period,
// waited before PV). 3 barriers/period. Atomic O/rowsum epilogue.
__global__ __launch_bounds__(256, 3) void mlstm_partial_kernel(
    const float* __restrict__ q, const short* __restrict__ Kg, const short* __restrict__ Vg,
    const float* __restrict__ a_arr, const float* __restrict__ m_arr,
    float* __restrict__ outp, float* __restrict__ rsacc) {
  __shared__ alignas(16) short Kst[2][8192];   // [dbuf][32k x 256d swz]
  __shared__ alignas(16) short Vst[8192];      // single [256d x 32j swz]
  __shared__ alignas(16) short plds[4][16*36];
  const int w = threadIdx.x >> 6, lane = threadIdx.x & 63;
  const int lr = lane & 15, g = lane >> 4;
  int pi, it, bh;
  if (blockIdx.x < 256) { pi = 0; bh = blockIdx.x & 7; it = 31 - (int)(blockIdx.x >> 3); }
  else { const int j = blockIdx.x - 256; pi = 1; bh = j & 7; it = j >> 3; }
  const int b = bh >> 2, h = bh & 3;
  const int R0 = it*64 + w*16;            // wave's 16 rows
  const long arow = (long)bh * S_LEN;
  const int np = it + 1;                  // staged periods (tiles 2p+pi)
  const int dmax = 2*it + (w >> 1) - pi;
  const int pmax = (dmax >= 0) ? (dmax >> 1) : -1;   // wave computes p <= pmax
  const f32x4 zz = {0.f,0.f,0.f,0.f};
  const int sw = (lr & 7) << 3;

  // Q fragments for the wave's 16 rows, cast inline from fp32 source
  bf16x8 qf[8];
  const float* qsrc = q + ((long)(b*S_LEN + R0 + lr))*HID + h*DHD + g*8;
#pragma unroll
  for (int c8 = 0; c8 < 8; c8++) {
    f32x4 u0 = *(const f32x4*)(qsrc + c8*32);
    f32x4 u1 = *(const f32x4*)(qsrc + c8*32 + 4);
    qf[c8] = pack8(u0, u1);
  }
  float mrow[4];
#pragma unroll
  for (int r = 0; r < 4; r++) mrow[r] = m_arr[arow + R0 + g*4 + r];

  f32x4 oacc[16];
#pragma unroll
  for (int t = 0; t < 16; t++) oacc[t] = zz;
  float rs[4] = {0.f,0.f,0.f,0.f};
  short* myp = plds[w];

  // wave w stages quarter w of a tile (4 DMAs each)
  auto STAGE_K = [&](int pb, int p) {
    const int jts = 2*p + pi;
    const long toff = ((long)bh*64 + jts)*8192 + w*2048 + lane*8;
    short* kdst = &Kst[pb][w*2048];
    const short* ksrc = Kg + toff;
#pragma unroll
    for (int u = 0; u < 4; u++) gload16(ksrc + u*512, kdst + u*512);
  };
  auto STAGE_V = [&](int p) {
    const int jts = 2*p + pi;
    const long toff = ((long)bh*64 + jts)*8192 + w*2048 + lane*8;
    short* vdst = &Vst[w*2048];
    const short* vsrc = Vg + toff;
#pragma unroll
    for (int u = 0; u < 4; u++) gload16(vsrc + u*512, vdst + u*512);
  };

  float aC0, aC1, aN0 = 0.f, aN1 = 0.f;
  STAGE_K(0, 0);                          // K(0) in flight before period 0
  { const int j0 = pi*32;
    aC0 = a_arr[arow + j0 + lr]; aC1 = a_arr[arow + j0 + 16 + lr]; }

  for (int p = 0; p < np; ++p) {
    const int pb = p & 1;
    const bool more = (p + 1 < np);
    STAGE_V(p);                           // V(p): single buffer, used this period
    if (more) {
      STAGE_K(pb ^ 1, p + 1);             // K(p+1) prefetch
      const int j0 = (2*(p+1) + pi)*32;
      aN0 = a_arr[arow + j0 + lr]; aN1 = a_arr[arow + j0 + 16 + lr];
    }
    // W1: drain K(p). DMAs younger than K(p): V(p)4 (+K(p+1)4 if more).
    if (more) asm volatile("s_waitcnt vmcnt(8)" ::: "memory");
    else      asm volatile("s_waitcnt vmcnt(4)" ::: "memory");
    __builtin_amdgcn_s_barrier();         // K(p) quarters visible to all waves

    bf16x8 pa;
    const bool act = (p <= pmax);
    if (act) {
      const int j0 = (2*p + pi)*32;
      const short* Kt = &Kst[pb][0];
      f32x4 s0 = zz, s1 = zz;
      __builtin_amdgcn_s_setprio(1);
#pragma unroll
      for (int c8 = 0; c8 < 8; c8++) {
        const int ko = lr*256 + ((c8*32 + g*8) ^ sw);
        bf16x8 k0 = *(const bf16x8*)&Kt[ko];
        bf16x8 k1 = *(const bf16x8*)&Kt[ko + 4096];
        s0 = __builtin_amdgcn_mfma_f32_16x16x32_bf16(qf[c8], k0, s0, 0, 0, 0);
        s1 = __builtin_amdgcn_mfma_f32_16x16x32_bf16(qf[c8], k1, s1, 0, 0, 0);
      }
      __builtin_amdgcn_s_setprio(0);
      const bool needmask = (j0 + 31 > R0);
#pragma unroll
      for (int r = 0; r < 4; r++) {
        const int i = R0 + g*4 + r;
        float p0 = s0[r] * 0.0625f * __expf(aC0 - mrow[r]);
        float p1 = s1[r] * 0.0625f * __expf(aC1 - mrow[r]);
        if (needmask) {               // causal mask, diagonal tiles only
          if (j0 + lr > i)      p0 = 0.f;
          if (j0 + 16 + lr > i) p1 = 0.f;
        }
        rs[r] += p0 + p1;
        myp[(g*4 + r)*36 + lr]      = f2b(p0);
        myp[(g*4 + r)*36 + 16 + lr] = f2b(p1);
      }
      // re-fragment P (C-layout) -> A-layout via per-wave LDS
      const short* rp = myp + lr*36 + g*8;
      short4v plo = *(const short4v*)rp;
      short4v phi = *(const short4v*)(rp + 4);
      pa = bf16x8{plo[0],plo[1],plo[2],plo[3],phi[0],phi[1],phi[2],phi[3]};
    }
    // W2: drain V(p). DMAs younger than V(p): K(p+1)4 if more, else none.
    if (more) asm volatile("s_waitcnt vmcnt(4)" ::: "memory");
    else      asm volatile("s_waitcnt vmcnt(0)" ::: "memory");
    __builtin_amdgcn_s_barrier();         // V(p) quarters visible to all waves

    if (act) {
      __builtin_amdgcn_s_setprio(1);
#pragma unroll
      for (int t = 0; t < 16; t++) {
        const int d = t*16 + lr;
        const int vo = d*32 + ((g*8) ^ (((d >> 1) & 3) << 3));
        bf16x8 vf = *(const bf16x8*)&Vst[vo];
        oacc[t] = __builtin_amdgcn_mfma_f32_16x16x32_bf16(pa, vf, oacc[t], 0, 0, 0);
      }
      __builtin_amdgcn_s_setprio(0);
    }
    __builtin_amdgcn_s_barrier();         // PV reads done before V(p+1) lands
    if (more) { aC0 = aN0; aC1 = aN1; }
  }

  // rowsum reduce over the 16 key-columns
#pragma unroll
  for (int r = 0; r < 4; r++)
    for (int mk = 1; mk < 16; mk <<= 1)
      rs[r] += __shfl_xor(rs[r], mk);

  // atomic-accumulate partial O + rowsums
#pragma unroll
  for (int r = 0; r < 4; r++) {
    const int i = R0 + g*4 + r;
    float* orow = outp + ((long)(b*S_LEN + i))*HID + h*DHD + lr;
#pragma unroll
    for (int t = 0; t < 16; t++)
      unsafeAtomicAdd(orow + t*16, oacc[t][r]);
    if (lr == 0)
      unsafeAtomicAdd(&rsacc[arow + i], rs[r]);
  }
}

// ---- kernel 4: finalize — normalizer + per-head LayerNorm (verbatim R10) ----
__global__ __launch_bounds__(256) void finalize_kernel(
    float* __restrict__ outp, const float* __restrict__ rsacc,
    const float* __restrict__ nf_arr, const float* __restrict__ lns) {
  const int bi = blockIdx.x;                  // b*S + i
  const int h = threadIdx.x >> 6, lane = threadIdx.x & 63;
  const int b = bi >> 11, i = bi & (S_LEN-1);
  const int bh = b*NHEAD + h;
  const long roff = (long)bi * HID + (long)h*DHD;
  f32x4 xv = *(const f32x4*)(outp + roff + lane*4);
  const float rsv = rsacc[(long)bh*S_LEN + i];
  const float nfv = nf_arr[(long)bh*S_LEN + i];
  const float inv = 1.f / (fmaxf(fabsf(rsv), nfv) + 1e-6f);
  xv[0]*=inv; xv[1]*=inv; xv[2]*=inv; xv[3]*=inv;
  float sum = xv[0]+xv[1]+xv[2]+xv[3];
  float sq  = xv[0]*xv[0]+xv[1]*xv[1]+xv[2]*xv[2]+xv[3]*xv[3];
  for (int mk = 1; mk < 64; mk <<= 1) {
    sum += __shfl_xor(sum, mk);
    sq  += __shfl_xor(sq,  mk);
  }
  const float mean = sum * (1.f/256.f);
  const float var  = sq * (1.f/256.f) - mean*mean;
  const float rstd = rsqrtf(var + 1e-5f);
  f32x4 sc = *(const f32x4*)(lns + h*DHD + lane*4);
  f32x4 o;
  o[0]=(xv[0]-mean)*rstd*sc[0]; o[1]=(xv[1]-mean)*rstd*sc[1];
  o[2]=(xv[2]-mean)*rstd*sc[2]; o[3]=(xv[3]-mean)*rstd*sc[3];
  *(f32x4*)(outp + roff + lane*4) = o;
}

extern "C" void kernel_launch(void* const* d_in, const int* in_sizes, int n_in,
                              void* d_out, int out_size, void* d_ws, size_t ws_size,
                              hipStream_t stream) {
  const float* q   = (const float*)d_in[0];
  const float* k   = (const float*)d_in[1];
  const float* v   = (const float*)d_in[2];
  const float* wi  = (const float*)d_in[3];
  const float* bi  = (const float*)d_in[4];
  const float* wf  = (const float*)d_in[5];
  const float* bf_ = (const float*)d_in[6];
  const float* lns = (const float*)d_in[7];
  float* outp = (float*)d_out;

  char* ws = (char*)d_ws;
  const long nelem = (long)BH_CNT * S_LEN * DHD;      // 4,194,304
  short* Kg  = (short*)ws;
  short* Vg  = Kg + nelem;
  float* igA = (float*)(ws + 2*nelem*sizeof(short));
  float* fgA = igA + (long)BATCH*S_LEN*NHEAD;
  float* aA  = fgA + (long)BATCH*S_LEN*NHEAD;
  float* mA  = aA + (long)BH_CNT*S_LEN;
  float* nfA = mA + (long)BH_CNT*S_LEN;
  float* rsA = nfA + (long)BH_CNT*S_LEN;

  // zero accumulators: gates, output, rowsums
  hipMemsetAsync(igA, 0, 2 * (size_t)BATCH*S_LEN*NHEAD * sizeof(float), stream);
  hipMemsetAsync(outp, 0, (size_t)out_size * sizeof(float), stream);
  hipMemsetAsync(rsA, 0, (size_t)BH_CNT * S_LEN * sizeof(float), stream);

  prep_kernel<<<3328, 256, 0, stream>>>(q, k, v, wi, wf, Kg, Vg, igA, fgA);
  scan_kernel<<<BH_CNT, 256, 0, stream>>>(igA, fgA, bi, bf_, aA, mA, nfA);
  mlstm_partial_kernel<<<512, 256, 0, stream>>>(q, Kg, Vg, aA, mA, outp, rsA);
  finalize_kernel<<<BATCH*S_LEN, 256, 0, stream>>>(outp, rsA, nfA, lns);
}